// Round 2
// baseline (242.022 us; speedup 1.0000x reference)
//
#include <hip/hip_runtime.h>
#include <hip/hip_bf16.h>

typedef __bf16 bf16;
typedef __bf16 bf16x8 __attribute__((ext_vector_type(8)));
typedef float floatx4 __attribute__((ext_vector_type(4)));

// B=2, T=512, C=8, D=512, H=8, dk=64. M = B*T*C = 8192.
// ws regions (R = 8192*512 bf16 = 8.39 MB): r0 r1 r2 r3 | WT (2 MB) = 35.6 MB
// Chain: wtr -> WT ; gemm_qkv (fp32 A direct, z=3 merged, 64x128 tile, dbuf):
//   q->r0 (Q, pre-scaled 0.125, [hd][t][d]), k->r1 (K, [hd][t][d]),
//   v->r2 (V^T, [hd][d][t]) ; attn (r0,r1,r2)->r3 ; gemm_o r3 -> d_out.

#define AS1 __attribute__((address_space(1)))
#define AS3 __attribute__((address_space(3)))

__device__ __forceinline__ void gload_lds16(const bf16* g, bf16* l) {
    __builtin_amdgcn_global_load_lds((const AS1 unsigned int*)g,
                                     (AS3 unsigned int*)l, 16, 0, 0);
}

union Pack8 { bf16 h[8]; uint4 u; };

// ---------------- weight transpose W[K][N] fp32 -> WT[N][K] bf16 -------------
__global__ __launch_bounds__(256) void wtr_kernel(
    const float* __restrict__ Wq, const float* __restrict__ Wk,
    const float* __restrict__ Wv, const float* __restrict__ Wo,
    bf16* __restrict__ WT)
{
    __shared__ float Ts[64][65];
    const int tid = threadIdx.x;
    const int k0 = blockIdx.x * 64;
    const int n0 = blockIdx.y * 64;
    const int z  = blockIdx.z;
    const float* W = (z == 0) ? Wq : (z == 1) ? Wk : (z == 2) ? Wv : Wo;
    bf16* O = WT + (size_t)z * 512 * 512;
    #pragma unroll
    for (int i = 0; i < 16; i++) {
        const int r = i * 4 + (tid >> 6), c = tid & 63;
        Ts[r][c] = W[(size_t)(k0 + r) * 512 + n0 + c];
    }
    __syncthreads();
    #pragma unroll
    for (int i = 0; i < 16; i++) {
        const int a = i * 4 + (tid >> 6), c = tid & 63;
        O[(size_t)(n0 + a) * 512 + k0 + c] = (bf16)Ts[c][a];
    }
}

// ---------------- merged Q/K/V projection GEMM ------------------------------
// 64x128 tile, double-buffered LDS, 2-phase prefetch (issue t+1 loads before
// computing t; single barrier per iter so the vmcnt drain lands AFTER MFMA).
// A fp32 reg-staged + converted; B bf16 via global_load_lds.
// Waves 2x2: wave covers 32x64 (acc[2][4]).
__global__ __launch_bounds__(256, 4) void gemm_qkv(
    const float* __restrict__ Aq, const float* __restrict__ Ak,
    const float* __restrict__ Av, const bf16* __restrict__ WT,
    const float* __restrict__ Bq, const float* __restrict__ Bk,
    const float* __restrict__ Bv,
    bf16* __restrict__ Oq, bf16* __restrict__ Ok, bf16* __restrict__ Ov)
{
    __shared__ bf16 Asm[2][64 * 32];
    __shared__ bf16 Bsm[2][128 * 32];
    const int z = blockIdx.z;
    const float* A    = (z == 0) ? Aq : (z == 1) ? Ak : Av;
    const float* bias = (z == 0) ? Bq : (z == 1) ? Bk : Bv;
    bf16* out         = (z == 0) ? Oq : (z == 1) ? Ok : Ov;
    const bf16* BT = WT + (size_t)z * 262144;
    const float scale = (z == 0) ? 0.125f : 1.0f;

    const int tid  = threadIdx.x;
    const int lane = tid & 63;
    const int wave = tid >> 6;
    const int quad = lane >> 4;
    const int l16  = lane & 15;
    const int mblk = blockIdx.x * 64;
    const int nblk = blockIdx.y * 128;

    const int srow = wave * 16 + (lane >> 2);
    const int scol = (lane & 3) * 8;
    const float* Ag = A + (size_t)(mblk + srow) * 512 + scol;
    const bf16* Bg0 = BT + (size_t)(nblk + srow) * 512 + scol;
    const bf16* Bg1 = Bg0 + (size_t)64 * 512;
    const int aoff  = srow * 32 + scol;      // per-lane A write offset
    const int b0off = wave * 16 * 32;        // wave-uniform lds-DMA bases
    const int b1off = (64 + wave * 16) * 32;

    const int wr = (wave >> 1) * 32;
    const int wc = (wave & 1) * 64;

    floatx4 acc[2][4] = {};

    // prologue: stage tile 0 into buf 0
    {
        gload_lds16(Bg0, Bsm[0] + b0off);
        gload_lds16(Bg1, Bsm[0] + b1off);
        float4 x0 = *(const float4*)(Ag);
        float4 x1 = *(const float4*)(Ag + 4);
        Pack8 pa;
        pa.h[0] = (bf16)x0.x; pa.h[1] = (bf16)x0.y;
        pa.h[2] = (bf16)x0.z; pa.h[3] = (bf16)x0.w;
        pa.h[4] = (bf16)x1.x; pa.h[5] = (bf16)x1.y;
        pa.h[6] = (bf16)x1.z; pa.h[7] = (bf16)x1.w;
        *(uint4*)(Asm[0] + aoff) = pa.u;
        __syncthreads();
    }

    #pragma unroll 2
    for (int t = 0; t < 16; t++) {
        const int cur = t & 1;
        float4 x0, x1;
        if (t < 15) {
            const int k1 = (t + 1) * 32;
            gload_lds16(Bg0 + k1, Bsm[cur ^ 1] + b0off);
            gload_lds16(Bg1 + k1, Bsm[cur ^ 1] + b1off);
            x0 = *(const float4*)(Ag + k1);
            x1 = *(const float4*)(Ag + k1 + 4);
        }
        bf16x8 a[2], b[4];
        #pragma unroll
        for (int mt = 0; mt < 2; mt++)
            a[mt] = *(const bf16x8*)(Asm[cur] + (wr + mt * 16 + l16) * 32 + quad * 8);
        #pragma unroll
        for (int nt = 0; nt < 4; nt++)
            b[nt] = *(const bf16x8*)(Bsm[cur] + (wc + nt * 16 + l16) * 32 + quad * 8);
        #pragma unroll
        for (int mt = 0; mt < 2; mt++)
            #pragma unroll
            for (int nt = 0; nt < 4; nt++)
                acc[mt][nt] = __builtin_amdgcn_mfma_f32_16x16x32_bf16(
                    a[mt], b[nt], acc[mt][nt], 0, 0, 0);
        if (t < 15) {
            Pack8 pa;
            pa.h[0] = (bf16)x0.x; pa.h[1] = (bf16)x0.y;
            pa.h[2] = (bf16)x0.z; pa.h[3] = (bf16)x0.w;
            pa.h[4] = (bf16)x1.x; pa.h[5] = (bf16)x1.y;
            pa.h[6] = (bf16)x1.z; pa.h[7] = (bf16)x1.w;
            *(uint4*)(Asm[cur ^ 1] + aoff) = pa.u;
        }
        __syncthreads();
    }

    #pragma unroll
    for (int mt = 0; mt < 2; mt++) {
        #pragma unroll
        for (int nt = 0; nt < 4; nt++) {
            const int colg = nblk + wc + nt * 16 + l16;
            const float bb = bias[colg];
            #pragma unroll
            for (int r = 0; r < 4; r++) {
                const int rowg = mblk + wr + mt * 16 + quad * 4 + r;
                const float v = (acc[mt][nt][r] + bb) * scale;
                const int b_ = rowg >> 12;
                const int t_ = (rowg >> 3) & 511;
                const int c  = rowg & 7;
                const int h  = colg >> 6;
                const int d  = colg & 63;
                const int hd = b_ * 64 + h * 8 + c;
                const size_t addr = (z == 2)
                    ? ((size_t)hd * 64 + d) * 512 + t_
                    : ((size_t)hd * 512 + t_) * 64 + d;
                out[addr] = (bf16)v;
            }
        }
    }
}

// ---------------- output projection GEMM (bf16 A, fp32 out) ------------------
// Same 64x128 dbuf 2-phase structure; A also via global_load_lds.
__global__ __launch_bounds__(256, 6) void gemm_o(
    const bf16* __restrict__ A, const bf16* __restrict__ BT,
    const float* __restrict__ bias, float* __restrict__ out)
{
    __shared__ bf16 Asm[2][64 * 32];
    __shared__ bf16 Bsm[2][128 * 32];
    const int tid  = threadIdx.x;
    const int lane = tid & 63;
    const int wave = tid >> 6;
    const int quad = lane >> 4;
    const int l16  = lane & 15;
    const int mblk = blockIdx.x * 64;
    const int nblk = blockIdx.y * 128;

    const int srow = wave * 16 + (lane >> 2);
    const int scol = (lane & 3) * 8;
    const bf16* Ag  = A + (size_t)(mblk + srow) * 512 + scol;
    const bf16* Bg0 = BT + (size_t)(nblk + srow) * 512 + scol;
    const bf16* Bg1 = Bg0 + (size_t)64 * 512;
    const int a0off = wave * 16 * 32;
    const int b0off = wave * 16 * 32;
    const int b1off = (64 + wave * 16) * 32;

    const int wr = (wave >> 1) * 32;
    const int wc = (wave & 1) * 64;

    floatx4 acc[2][4] = {};

    gload_lds16(Ag,  Asm[0] + a0off);
    gload_lds16(Bg0, Bsm[0] + b0off);
    gload_lds16(Bg1, Bsm[0] + b1off);
    __syncthreads();

    #pragma unroll 2
    for (int t = 0; t < 16; t++) {
        const int cur = t & 1;
        if (t < 15) {
            const int k1 = (t + 1) * 32;
            gload_lds16(Ag + k1,  Asm[cur ^ 1] + a0off);
            gload_lds16(Bg0 + k1, Bsm[cur ^ 1] + b0off);
            gload_lds16(Bg1 + k1, Bsm[cur ^ 1] + b1off);
        }
        bf16x8 a[2], b[4];
        #pragma unroll
        for (int mt = 0; mt < 2; mt++)
            a[mt] = *(const bf16x8*)(Asm[cur] + (wr + mt * 16 + l16) * 32 + quad * 8);
        #pragma unroll
        for (int nt = 0; nt < 4; nt++)
            b[nt] = *(const bf16x8*)(Bsm[cur] + (wc + nt * 16 + l16) * 32 + quad * 8);
        #pragma unroll
        for (int mt = 0; mt < 2; mt++)
            #pragma unroll
            for (int nt = 0; nt < 4; nt++)
                acc[mt][nt] = __builtin_amdgcn_mfma_f32_16x16x32_bf16(
                    a[mt], b[nt], acc[mt][nt], 0, 0, 0);
        __syncthreads();
    }

    #pragma unroll
    for (int mt = 0; mt < 2; mt++) {
        #pragma unroll
        for (int nt = 0; nt < 4; nt++) {
            const int colg = nblk + wc + nt * 16 + l16;
            const float bb = bias[colg];
            #pragma unroll
            for (int r = 0; r < 4; r++) {
                const int rowg = mblk + wr + mt * 16 + quad * 4 + r;
                out[(size_t)rowg * 512 + colg] = acc[mt][nt][r] + bb;
            }
        }
    }
}

// ---------------- attention ---------------------------------------------------
// vs round 1: mask LDS phase removed — mask loaded directly per (nt,r) as a
// 64B-coalesced dword (L2/L3-resident, shared by the XCD's 16 heads). One
// fewer barrier, ~150 fewer insts/wave, LDS only holds P + reductions.
#define PST 520

__global__ __launch_bounds__(256, 8) void attn_kernel(
    const bf16* __restrict__ Qws, const bf16* __restrict__ Kws,
    const bf16* __restrict__ Vtws, const int* __restrict__ mask,
    bf16* __restrict__ Xws)
{
    __shared__ bf16 Psm[16][PST];
    __shared__ float redM[4][16];
    __shared__ float redS[4][16];
    const int tid  = threadIdx.x;
    const int wave = tid >> 6;
    const int lane = tid & 63;
    const int quad = lane >> 4;
    const int l16  = lane & 15;
    // XCD swizzle: XCD x owns heads [x*16, x*16+16); qt varies fastest.
    const int s_ = blockIdx.x;
    const int o_ = ((s_ & 7) << 9) | (s_ >> 3);
    const int qt = o_ & 31;
    const int hd = o_ >> 5;
    const int q0 = qt * 16;
    const int b = hd >> 6;
    const int h = (hd >> 3) & 7;
    const int c = hd & 7;

    const int* mp = mask + ((size_t)b * 512 + q0) * 512;
    const bf16* Qh = Qws + (size_t)hd * 512 * 64;
    const bf16* Kh = Kws + (size_t)hd * 512 * 64;
    bf16x8 aq0 = *(const bf16x8*)(Qh + (size_t)(q0 + l16) * 64 + quad * 8);
    bf16x8 aq1 = *(const bf16x8*)(Qh + (size_t)(q0 + l16) * 64 + 32 + quad * 8);

    float sv[8][4];
    float mx[4] = {-3.0e38f, -3.0e38f, -3.0e38f, -3.0e38f};
    #pragma unroll
    for (int nt = 0; nt < 8; nt++) {
        const int s0 = wave * 128 + nt * 16;
        bf16x8 bk0 = *(const bf16x8*)(Kh + (size_t)(s0 + l16) * 64 + quad * 8);
        bf16x8 bk1 = *(const bf16x8*)(Kh + (size_t)(s0 + l16) * 64 + 32 + quad * 8);
        floatx4 s = {};
        s = __builtin_amdgcn_mfma_f32_16x16x32_bf16(aq0, bk0, s, 0, 0, 0);
        s = __builtin_amdgcn_mfma_f32_16x16x32_bf16(aq1, bk1, s, 0, 0, 0);
        #pragma unroll
        for (int r = 0; r < 4; r++) {
            const int mv = mp[(size_t)(quad * 4 + r) * 512 + s0 + l16];
            const float v = s[r] + ((mv == 0) ? -1.0e9f : 0.0f);
            sv[nt][r] = v;
            mx[r] = fmaxf(mx[r], v);
        }
    }
    #pragma unroll
    for (int off = 1; off < 16; off <<= 1)
        #pragma unroll
        for (int r = 0; r < 4; r++)
            mx[r] = fmaxf(mx[r], __shfl_xor(mx[r], off, 64));
    if (l16 == 0)
        #pragma unroll
        for (int r = 0; r < 4; r++) redM[wave][quad * 4 + r] = mx[r];
    __syncthreads();
    float mf[4], sum[4] = {0.f, 0.f, 0.f, 0.f};
    #pragma unroll
    for (int r = 0; r < 4; r++) {
        const int qr = quad * 4 + r;
        mf[r] = fmaxf(fmaxf(redM[0][qr], redM[1][qr]),
                      fmaxf(redM[2][qr], redM[3][qr]));
    }
    #pragma unroll
    for (int nt = 0; nt < 8; nt++)
        #pragma unroll
        for (int r = 0; r < 4; r++) {
            const float e = __expf(sv[nt][r] - mf[r]);
            sv[nt][r] = e;
            sum[r] += e;
        }
    #pragma unroll
    for (int off = 1; off < 16; off <<= 1)
        #pragma unroll
        for (int r = 0; r < 4; r++)
            sum[r] += __shfl_xor(sum[r], off, 64);
    if (l16 == 0)
        #pragma unroll
        for (int r = 0; r < 4; r++) redS[wave][quad * 4 + r] = sum[r];
    __syncthreads();
    float inv[4];
    #pragma unroll
    for (int r = 0; r < 4; r++) {
        const int qr = quad * 4 + r;
        inv[r] = 1.f / (redS[0][qr] + redS[1][qr] + redS[2][qr] + redS[3][qr]);
    }
    #pragma unroll
    for (int nt = 0; nt < 8; nt++)
        #pragma unroll
        for (int r = 0; r < 4; r++)
            Psm[quad * 4 + r][wave * 128 + nt * 16 + l16] =
                (bf16)(sv[nt][r] * inv[r]);
    __syncthreads();

    const bf16* Vh = Vtws + (size_t)hd * 64 * 512;
    const int d0 = wave * 16;
    floatx4 oacc = {};
    #pragma unroll
    for (int ks = 0; ks < 16; ks++) {
        bf16x8 ap = *(const bf16x8*)(&Psm[l16][ks * 32 + quad * 8]);
        bf16x8 bv = *(const bf16x8*)(Vh + (size_t)(d0 + l16) * 512 + ks * 32 + quad * 8);
        oacc = __builtin_amdgcn_mfma_f32_16x16x32_bf16(ap, bv, oacc, 0, 0, 0);
    }
    #pragma unroll
    for (int r = 0; r < 4; r++) {
        const int q = quad * 4 + r;
        const size_t row = ((size_t)b * 512 + q0 + q) * 8 + c;
        Xws[row * 512 + h * 64 + d0 + l16] = (bf16)oacc[r];
    }
}

extern "C" void kernel_launch(void* const* d_in, const int* in_sizes, int n_in,
                              void* d_out, int out_size, void* d_ws, size_t ws_size,
                              hipStream_t stream)
{
    const float* qin  = (const float*)d_in[0];
    const float* kin  = (const float*)d_in[1];
    const float* vin  = (const float*)d_in[2];
    const int*   mask = (const int*)d_in[3];
    const float* Bq = (const float*)d_in[5];
    const float* Bk = (const float*)d_in[7];
    const float* Bv = (const float*)d_in[9];
    const float* Bo = (const float*)d_in[11];
    float* out = (float*)d_out;

    const size_t R = (size_t)8192 * 512;
    bf16* r0 = (bf16*)d_ws;
    bf16* r1 = r0 + R;
    bf16* r2 = r1 + R;
    bf16* r3 = r2 + R;
    bf16* WT = r3 + R;

    wtr_kernel<<<dim3(8, 8, 4), dim3(256), 0, stream>>>(
        (const float*)d_in[4], (const float*)d_in[6],
        (const float*)d_in[8], (const float*)d_in[10], WT);
    gemm_qkv<<<dim3(128, 4, 3), dim3(256), 0, stream>>>(
        qin, kin, vin, WT, Bq, Bk, Bv, r0, r1, r2);
    attn_kernel<<<dim3(4096), dim3(256), 0, stream>>>(
        r0, r1, r2, mask, r3);
    gemm_o<<<dim3(128, 4), dim3(256), 0, stream>>>(
        r3, WT + (size_t)3 * 262144, Bo, out);
}

// Round 3
// 204.297 us; speedup vs baseline: 1.1847x; 1.1847x over previous
//
#include <hip/hip_runtime.h>
#include <hip/hip_bf16.h>

typedef __bf16 bf16;
typedef __bf16 bf16x8 __attribute__((ext_vector_type(8)));
typedef float floatx4 __attribute__((ext_vector_type(4)));

// B=2, T=512, C=8, D=512, H=8, dk=64. M = B*T*C = 8192.
// ws regions (R = 8192*512 bf16 = 8.39 MB): r0 r1 r2 r3 | WT (2 MB) = 35.6 MB
// Chain: wtr -> WT ; gemm_qkv (z=3 merged, 128x128, fp32-A reg-staged):
//   q->r0 (Q, pre-scaled 0.125, [hd][t][d]), k->r1 (K, [hd][t][d]),
//   v->r2 (V^T, [hd][d][t], LDS-transposed epilogue) ;
// attn QBLK=64 (r0,r1,r2)->r3 ; gemm_o r3 -> d_out.

#define AS1 __attribute__((address_space(1)))
#define AS3 __attribute__((address_space(3)))

__device__ __forceinline__ void gload_lds16(const bf16* g, bf16* l) {
    __builtin_amdgcn_global_load_lds((const AS1 unsigned int*)g,
                                     (AS3 unsigned int*)l, 16, 0, 0);
}

union Pack8 { bf16 h[8]; uint4 u; };

// ---------------- weight transpose W[K][N] fp32 -> WT[N][K] bf16 -------------
__global__ __launch_bounds__(256) void wtr_kernel(
    const float* __restrict__ Wq, const float* __restrict__ Wk,
    const float* __restrict__ Wv, const float* __restrict__ Wo,
    bf16* __restrict__ WT)
{
    __shared__ float Ts[64][65];
    const int tid = threadIdx.x;
    const int k0 = blockIdx.x * 64;
    const int n0 = blockIdx.y * 64;
    const int z  = blockIdx.z;
    const float* W = (z == 0) ? Wq : (z == 1) ? Wk : (z == 2) ? Wv : Wo;
    bf16* O = WT + (size_t)z * 512 * 512;
    #pragma unroll
    for (int i = 0; i < 16; i++) {
        const int r = i * 4 + (tid >> 6), c = tid & 63;
        Ts[r][c] = W[(size_t)(k0 + r) * 512 + n0 + c];
    }
    __syncthreads();
    #pragma unroll
    for (int i = 0; i < 16; i++) {
        const int a = i * 4 + (tid >> 6), c = tid & 63;
        O[(size_t)(n0 + a) * 512 + k0 + c] = (bf16)Ts[c][a];
    }
}

// ---------------- merged Q/K/V projection GEMM (round-1 structure) -----------
// 128x128 tile, single-buffer, A fp32 reg-staged + converted, B via
// global_load_lds. z=0: Q scaled 0.125 -> [hd][t][d]; z=1: K -> [hd][t][d];
// z=2: V^T -> [hd][d][t] via LDS-transpose epilogue (32B-contiguous stores
// instead of 2B scatter at 1KB stride).
__global__ __launch_bounds__(256) void gemm_qkv(
    const float* __restrict__ Aq, const float* __restrict__ Ak,
    const float* __restrict__ Av, const bf16* __restrict__ WT,
    const float* __restrict__ Bq, const float* __restrict__ Bk,
    const float* __restrict__ Bv,
    bf16* __restrict__ Oq, bf16* __restrict__ Ok, bf16* __restrict__ Ov)
{
    __shared__ bf16 Asm[128 * 32];
    __shared__ bf16 Bsm[128 * 32];
    __shared__ bf16 Tsm[128][136];   // z==2 transpose staging
    const int z = blockIdx.z;
    const float* A    = (z == 0) ? Aq : (z == 1) ? Ak : Av;
    const float* bias = (z == 0) ? Bq : (z == 1) ? Bk : Bv;
    bf16* out         = (z == 0) ? Oq : (z == 1) ? Ok : Ov;
    const bf16* BT = WT + (size_t)z * 262144;
    const float scale = (z == 0) ? 0.125f : 1.0f;

    const int tid  = threadIdx.x;
    const int lane = tid & 63;
    const int wave = tid >> 6;
    const int quad = lane >> 4;
    const int l16  = lane & 15;
    const int mblk = blockIdx.x * 128;
    const int nblk = blockIdx.y * 128;

    const int srow = wave * 16 + (lane >> 2);
    const int scol = (lane & 3) * 8;
    const float* Ag0 = A + (size_t)(mblk + srow) * 512 + scol;
    const float* Ag1 = Ag0 + (size_t)64 * 512;
    const bf16* Bg0 = BT + (size_t)(nblk + srow) * 512 + scol;
    const bf16* Bg1 = Bg0 + (size_t)64 * 512;
    bf16* Alp0 = Asm + srow * 32 + scol;
    bf16* Alp1 = Alp0 + 64 * 32;
    bf16* Bl0 = Bsm + wave * 16 * 32;
    bf16* Bl1 = Bsm + (64 + wave * 16) * 32;

    const int wr = (wave >> 1) * 64;
    const int wc = (wave & 1) * 64;

    floatx4 acc[4][4] = {};
    for (int k0 = 0; k0 < 512; k0 += 32) {
        gload_lds16(Bg0 + k0, Bl0);
        gload_lds16(Bg1 + k0, Bl1);
        float4 x0 = *(const float4*)(Ag0 + k0);
        float4 x1 = *(const float4*)(Ag0 + k0 + 4);
        float4 y0 = *(const float4*)(Ag1 + k0);
        float4 y1 = *(const float4*)(Ag1 + k0 + 4);
        Pack8 pa, pb;
        pa.h[0] = (bf16)x0.x; pa.h[1] = (bf16)x0.y;
        pa.h[2] = (bf16)x0.z; pa.h[3] = (bf16)x0.w;
        pa.h[4] = (bf16)x1.x; pa.h[5] = (bf16)x1.y;
        pa.h[6] = (bf16)x1.z; pa.h[7] = (bf16)x1.w;
        pb.h[0] = (bf16)y0.x; pb.h[1] = (bf16)y0.y;
        pb.h[2] = (bf16)y0.z; pb.h[3] = (bf16)y0.w;
        pb.h[4] = (bf16)y1.x; pb.h[5] = (bf16)y1.y;
        pb.h[6] = (bf16)y1.z; pb.h[7] = (bf16)y1.w;
        *(uint4*)Alp0 = pa.u;
        *(uint4*)Alp1 = pb.u;
        __syncthreads();
        bf16x8 a[4], b[4];
        #pragma unroll
        for (int mt = 0; mt < 4; mt++)
            a[mt] = *(const bf16x8*)(Asm + (wr + mt * 16 + l16) * 32 + quad * 8);
        #pragma unroll
        for (int nt = 0; nt < 4; nt++)
            b[nt] = *(const bf16x8*)(Bsm + (wc + nt * 16 + l16) * 32 + quad * 8);
        #pragma unroll
        for (int mt = 0; mt < 4; mt++)
            #pragma unroll
            for (int nt = 0; nt < 4; nt++)
                acc[mt][nt] = __builtin_amdgcn_mfma_f32_16x16x32_bf16(
                    a[mt], b[nt], acc[mt][nt], 0, 0, 0);
        __syncthreads();
    }

    if (z != 2) {
        #pragma unroll
        for (int mt = 0; mt < 4; mt++) {
            #pragma unroll
            for (int nt = 0; nt < 4; nt++) {
                const int colg = nblk + wc + nt * 16 + l16;
                const float bb = bias[colg];
                #pragma unroll
                for (int r = 0; r < 4; r++) {
                    const int rowg = mblk + wr + mt * 16 + quad * 4 + r;
                    const float v = (acc[mt][nt][r] + bb) * scale;
                    const int b_ = rowg >> 12;
                    const int t_ = (rowg >> 3) & 511;
                    const int c  = rowg & 7;
                    const int h  = colg >> 6;
                    const int d  = colg & 63;
                    const int hd = b_ * 64 + h * 8 + c;
                    out[((size_t)hd * 512 + t_) * 64 + d] = (bf16)v;
                }
            }
        }
    } else {
        // stage the 128x128 output tile (bias applied) into LDS
        #pragma unroll
        for (int mt = 0; mt < 4; mt++) {
            #pragma unroll
            for (int nt = 0; nt < 4; nt++) {
                const int cl = wc + nt * 16 + l16;
                const float bb = bias[nblk + cl];
                #pragma unroll
                for (int r = 0; r < 4; r++)
                    Tsm[wr + mt * 16 + quad * 4 + r][cl] =
                        (bf16)(acc[mt][nt][r] + bb);
            }
        }
        __syncthreads();
        // rows of block = 16 t x 8 c; store 16-t runs (32B) per (col, c)
        const int b_ = mblk >> 12;
        const int t0 = (mblk >> 3) & 511;
        #pragma unroll
        for (int ch = tid; ch < 1024; ch += 256) {
            const int col = ch >> 3, c = ch & 7;
            const int h = (nblk + col) >> 6, d = (nblk + col) & 63;
            const int hd = b_ * 64 + h * 8 + c;
            Pack8 lo, hi;
            #pragma unroll
            for (int j = 0; j < 8; j++) lo.h[j] = Tsm[j * 8 + c][col];
            #pragma unroll
            for (int j = 0; j < 8; j++) hi.h[j] = Tsm[(j + 8) * 8 + c][col];
            bf16* dst = out + ((size_t)hd * 64 + d) * 512 + t0;
            *(uint4*)dst = lo.u;
            *(uint4*)(dst + 8) = hi.u;
        }
    }
}

// ---------------- output projection GEMM (128x128, round-1 structure) --------
__global__ __launch_bounds__(256) void gemm_o(
    const bf16* __restrict__ A, const bf16* __restrict__ BT,
    const float* __restrict__ bias, float* __restrict__ out)
{
    __shared__ bf16 Asm[128 * 32];
    __shared__ bf16 Bsm[128 * 32];
    const int tid  = threadIdx.x;
    const int lane = tid & 63;
    const int wave = tid >> 6;
    const int quad = lane >> 4;
    const int l16  = lane & 15;
    const int mblk = blockIdx.x * 128;
    const int nblk = blockIdx.y * 128;

    const int srow = wave * 16 + (lane >> 2);
    const int scol = (lane & 3) * 8;
    const bf16* Ag0 = A + (size_t)(mblk + srow) * 512 + scol;
    const bf16* Ag1 = Ag0 + (size_t)64 * 512;
    const bf16* Bg0 = BT + (size_t)(nblk + srow) * 512 + scol;
    const bf16* Bg1 = Bg0 + (size_t)64 * 512;
    bf16* Al0 = Asm + wave * 16 * 32;
    bf16* Al1 = Asm + (64 + wave * 16) * 32;
    bf16* Bl0 = Bsm + wave * 16 * 32;
    bf16* Bl1 = Bsm + (64 + wave * 16) * 32;

    const int wr = (wave >> 1) * 64;
    const int wc = (wave & 1) * 64;

    floatx4 acc[4][4] = {};
    for (int k0 = 0; k0 < 512; k0 += 32) {
        gload_lds16(Ag0 + k0, Al0);
        gload_lds16(Ag1 + k0, Al1);
        gload_lds16(Bg0 + k0, Bl0);
        gload_lds16(Bg1 + k0, Bl1);
        __syncthreads();
        bf16x8 a[4], b[4];
        #pragma unroll
        for (int mt = 0; mt < 4; mt++)
            a[mt] = *(const bf16x8*)(Asm + (wr + mt * 16 + l16) * 32 + quad * 8);
        #pragma unroll
        for (int nt = 0; nt < 4; nt++)
            b[nt] = *(const bf16x8*)(Bsm + (wc + nt * 16 + l16) * 32 + quad * 8);
        #pragma unroll
        for (int mt = 0; mt < 4; mt++)
            #pragma unroll
            for (int nt = 0; nt < 4; nt++)
                acc[mt][nt] = __builtin_amdgcn_mfma_f32_16x16x32_bf16(
                    a[mt], b[nt], acc[mt][nt], 0, 0, 0);
        __syncthreads();
    }

    #pragma unroll
    for (int mt = 0; mt < 4; mt++) {
        #pragma unroll
        for (int nt = 0; nt < 4; nt++) {
            const int colg = nblk + wc + nt * 16 + l16;
            const float bb = bias[colg];
            #pragma unroll
            for (int r = 0; r < 4; r++) {
                const int rowg = mblk + wr + mt * 16 + quad * 4 + r;
                out[(size_t)rowg * 512 + colg] = acc[mt][nt][r] + bb;
            }
        }
    }
}

// ---------------- attention: QBLK=64 per block -------------------------------
// Block = 64 q-rows x 1 head (full 512 keys). 4 waves; wave owns key range
// [wave*128, +128) for QK^T and d-slice [wave*16, +16) for PV. Scores fully
// register-resident (sv[4][8] floatx4 = 128 VGPR); K read once per block;
// mask amortized 4x vs QBLK=16. P via 64x520 LDS tile. 2 blocks/CU.
#define PST 520

__global__ __launch_bounds__(256, 2) void attn_kernel(
    const bf16* __restrict__ Qws, const bf16* __restrict__ Kws,
    const bf16* __restrict__ Vtws, const int* __restrict__ mask,
    bf16* __restrict__ Xws)
{
    __shared__ bf16 Psm[64][PST];
    __shared__ float redM[4][64];
    __shared__ float redS[4][64];
    const int tid  = threadIdx.x;
    const int wave = tid >> 6;
    const int lane = tid & 63;
    const int quad = lane >> 4;
    const int l16  = lane & 15;
    // XCD swizzle: 1024 blocks, XCD x owns heads [x*16, x*16+16).
    const int s_ = blockIdx.x;
    const int o_ = ((s_ & 7) << 7) | (s_ >> 3);
    const int hd = o_ >> 3;
    const int qt = o_ & 7;
    const int q0 = qt * 64;
    const int b = hd >> 6;
    const int h = (hd >> 3) & 7;
    const int c = hd & 7;

    const bf16* Qh = Qws + (size_t)hd * 512 * 64;
    const bf16* Kh = Kws + (size_t)hd * 512 * 64;
    const int* mp = mask + ((size_t)b * 512 + q0) * 512;

    bf16x8 aq[4][2];
    #pragma unroll
    for (int s = 0; s < 4; s++) {
        aq[s][0] = *(const bf16x8*)(Qh + (size_t)(q0 + s * 16 + l16) * 64 + quad * 8);
        aq[s][1] = *(const bf16x8*)(Qh + (size_t)(q0 + s * 16 + l16) * 64 + 32 + quad * 8);
    }

    floatx4 sv[4][8];
    #pragma unroll
    for (int s = 0; s < 4; s++)
        #pragma unroll
        for (int nt = 0; nt < 8; nt++)
            sv[s][nt] = (floatx4){0.f, 0.f, 0.f, 0.f};

    #pragma unroll
    for (int nt = 0; nt < 8; nt++) {
        const int s0 = wave * 128 + nt * 16;
        bf16x8 bk0 = *(const bf16x8*)(Kh + (size_t)(s0 + l16) * 64 + quad * 8);
        bf16x8 bk1 = *(const bf16x8*)(Kh + (size_t)(s0 + l16) * 64 + 32 + quad * 8);
        #pragma unroll
        for (int s = 0; s < 4; s++) {
            sv[s][nt] = __builtin_amdgcn_mfma_f32_16x16x32_bf16(
                aq[s][0], bk0, sv[s][nt], 0, 0, 0);
            sv[s][nt] = __builtin_amdgcn_mfma_f32_16x16x32_bf16(
                aq[s][1], bk1, sv[s][nt], 0, 0, 0);
        }
    }

    float mx[4][4];
    #pragma unroll
    for (int s = 0; s < 4; s++)
        #pragma unroll
        for (int r = 0; r < 4; r++)
            mx[s][r] = -3.0e38f;
    #pragma unroll
    for (int s = 0; s < 4; s++)
        #pragma unroll
        for (int nt = 0; nt < 8; nt++)
            #pragma unroll
            for (int r = 0; r < 4; r++) {
                const int mv = mp[(size_t)(s * 16 + quad * 4 + r) * 512 +
                                  wave * 128 + nt * 16 + l16];
                const float v = sv[s][nt][r] + ((mv == 0) ? -1.0e9f : 0.0f);
                sv[s][nt][r] = v;
                mx[s][r] = fmaxf(mx[s][r], v);
            }
    #pragma unroll
    for (int off = 1; off < 16; off <<= 1)
        #pragma unroll
        for (int s = 0; s < 4; s++)
            #pragma unroll
            for (int r = 0; r < 4; r++)
                mx[s][r] = fmaxf(mx[s][r], __shfl_xor(mx[s][r], off, 64));
    if (l16 == 0)
        #pragma unroll
        for (int s = 0; s < 4; s++)
            #pragma unroll
            for (int r = 0; r < 4; r++)
                redM[wave][s * 16 + quad * 4 + r] = mx[s][r];
    __syncthreads();

    float mf[4][4], sum[4][4];
    #pragma unroll
    for (int s = 0; s < 4; s++)
        #pragma unroll
        for (int r = 0; r < 4; r++) {
            const int qr = s * 16 + quad * 4 + r;
            mf[s][r] = fmaxf(fmaxf(redM[0][qr], redM[1][qr]),
                             fmaxf(redM[2][qr], redM[3][qr]));
            sum[s][r] = 0.f;
        }
    #pragma unroll
    for (int s = 0; s < 4; s++)
        #pragma unroll
        for (int nt = 0; nt < 8; nt++)
            #pragma unroll
            for (int r = 0; r < 4; r++) {
                const float e = __expf(sv[s][nt][r] - mf[s][r]);
                sv[s][nt][r] = e;
                sum[s][r] += e;
            }
    #pragma unroll
    for (int off = 1; off < 16; off <<= 1)
        #pragma unroll
        for (int s = 0; s < 4; s++)
            #pragma unroll
            for (int r = 0; r < 4; r++)
                sum[s][r] += __shfl_xor(sum[s][r], off, 64);
    if (l16 == 0)
        #pragma unroll
        for (int s = 0; s < 4; s++)
            #pragma unroll
            for (int r = 0; r < 4; r++)
                redS[wave][s * 16 + quad * 4 + r] = sum[s][r];
    __syncthreads();

    #pragma unroll
    for (int s = 0; s < 4; s++)
        #pragma unroll
        for (int r = 0; r < 4; r++) {
            const int qr = s * 16 + quad * 4 + r;
            const float inv = 1.f / (redS[0][qr] + redS[1][qr] +
                                     redS[2][qr] + redS[3][qr]);
            #pragma unroll
            for (int nt = 0; nt < 8; nt++)
                Psm[qr][wave * 128 + nt * 16 + l16] =
                    (bf16)(sv[s][nt][r] * inv);
        }
    __syncthreads();

    const bf16* Vh = Vtws + (size_t)hd * 64 * 512;
    const int d0 = wave * 16;
    floatx4 o[4] = {};
    #pragma unroll
    for (int ks = 0; ks < 16; ks++) {
        bf16x8 bv = *(const bf16x8*)(Vh + (size_t)(d0 + l16) * 512 + ks * 32 + quad * 8);
        #pragma unroll
        for (int rt = 0; rt < 4; rt++) {
            bf16x8 ap = *(const bf16x8*)(&Psm[rt * 16 + l16][ks * 32 + quad * 8]);
            o[rt] = __builtin_amdgcn_mfma_f32_16x16x32_bf16(ap, bv, o[rt], 0, 0, 0);
        }
    }
    #pragma unroll
    for (int rt = 0; rt < 4; rt++)
        #pragma unroll
        for (int r = 0; r < 4; r++) {
            const int q = q0 + rt * 16 + quad * 4 + r;
            const size_t row = ((size_t)b * 512 + q) * 8 + c;
            Xws[row * 512 + h * 64 + d0 + l16] = (bf16)o[rt][r];
        }
}

extern "C" void kernel_launch(void* const* d_in, const int* in_sizes, int n_in,
                              void* d_out, int out_size, void* d_ws, size_t ws_size,
                              hipStream_t stream)
{
    const float* qin  = (const float*)d_in[0];
    const float* kin  = (const float*)d_in[1];
    const float* vin  = (const float*)d_in[2];
    const int*   mask = (const int*)d_in[3];
    const float* Bq = (const float*)d_in[5];
    const float* Bk = (const float*)d_in[7];
    const float* Bv = (const float*)d_in[9];
    const float* Bo = (const float*)d_in[11];
    float* out = (float*)d_out;

    const size_t R = (size_t)8192 * 512;
    bf16* r0 = (bf16*)d_ws;
    bf16* r1 = r0 + R;
    bf16* r2 = r1 + R;
    bf16* r3 = r2 + R;
    bf16* WT = r3 + R;

    wtr_kernel<<<dim3(8, 8, 4), dim3(256), 0, stream>>>(
        (const float*)d_in[4], (const float*)d_in[6],
        (const float*)d_in[8], (const float*)d_in[10], WT);
    gemm_qkv<<<dim3(64, 4, 3), dim3(256), 0, stream>>>(
        qin, kin, vin, WT, Bq, Bk, Bv, r0, r1, r2);
    attn_kernel<<<dim3(1024), dim3(256), 0, stream>>>(
        r0, r1, r2, mask, r3);
    gemm_o<<<dim3(64, 4), dim3(256), 0, stream>>>(
        r3, WT + (size_t)3 * 262144, Bo, out);
}

// Round 4
// 193.488 us; speedup vs baseline: 1.2508x; 1.0559x over previous
//
#include <hip/hip_runtime.h>
#include <hip/hip_bf16.h>

typedef __bf16 bf16;
typedef __bf16 bf16x8 __attribute__((ext_vector_type(8)));
typedef float floatx4 __attribute__((ext_vector_type(4)));

// B=2, T=512, C=8, D=512, H=8, dk=64. M = B*T*C = 8192.
// ws regions (R = 8192*512 bf16 = 8.39 MB): r0 r1 r2 r3 | WT (2 MB) = 35.6 MB
// Chain: wtr -> WT ; gemm_qkv (z=3 merged, 128x128, 8 waves, fp32-A staged):
//   q->r0 (Q, pre-scaled 0.125, [hd][t][d]), k->r1 (K, [hd][t][d]),
//   v->r2 (V^T, [hd][d][t], LDS-transposed epilogue) ;
// attn QBLK=64 swapped-QK (r0,r1,r2)->r3 ; gemm_o r3 -> d_out.

#define AS1 __attribute__((address_space(1)))
#define AS3 __attribute__((address_space(3)))

__device__ __forceinline__ void gload_lds16(const bf16* g, bf16* l) {
    __builtin_amdgcn_global_load_lds((const AS1 unsigned int*)g,
                                     (AS3 unsigned int*)l, 16, 0, 0);
}

union Pack8 { bf16 h[8]; uint4 u; };
union Pack4 { bf16 h[4]; unsigned long long u; };

// ---------------- weight transpose W[K][N] fp32 -> WT[N][K] bf16 -------------
__global__ __launch_bounds__(256) void wtr_kernel(
    const float* __restrict__ Wq, const float* __restrict__ Wk,
    const float* __restrict__ Wv, const float* __restrict__ Wo,
    bf16* __restrict__ WT)
{
    __shared__ float Ts[64][65];
    const int tid = threadIdx.x;
    const int k0 = blockIdx.x * 64;
    const int n0 = blockIdx.y * 64;
    const int z  = blockIdx.z;
    const float* W = (z == 0) ? Wq : (z == 1) ? Wk : (z == 2) ? Wv : Wo;
    bf16* O = WT + (size_t)z * 512 * 512;
    #pragma unroll
    for (int i = 0; i < 16; i++) {
        const int r = i * 4 + (tid >> 6), c = tid & 63;
        Ts[r][c] = W[(size_t)(k0 + r) * 512 + n0 + c];
    }
    __syncthreads();
    #pragma unroll
    for (int i = 0; i < 16; i++) {
        const int a = i * 4 + (tid >> 6), c = tid & 63;
        O[(size_t)(n0 + a) * 512 + k0 + c] = (bf16)Ts[c][a];
    }
}

// ---------------- merged Q/K/V projection GEMM: 8 waves, 128x128, BK=32 ------
// Wave = 32x64 output (acc[2][4]); wave w stages rows [w*16, +16) of A (fp32
// reg-staged + cvt) and B (global_load_lds). 6 waves/SIMD when resident.
__global__ __launch_bounds__(512, 4) void gemm_qkv(
    const float* __restrict__ Aq, const float* __restrict__ Ak,
    const float* __restrict__ Av, const bf16* __restrict__ WT,
    const float* __restrict__ Bq, const float* __restrict__ Bk,
    const float* __restrict__ Bv,
    bf16* __restrict__ Oq, bf16* __restrict__ Ok, bf16* __restrict__ Ov)
{
    __shared__ bf16 Asm[128 * 32];
    __shared__ bf16 Bsm[128 * 32];
    __shared__ bf16 Tsm[128][136];   // z==2 transpose staging
    const int z = blockIdx.z;
    const float* A    = (z == 0) ? Aq : (z == 1) ? Ak : Av;
    const float* bias = (z == 0) ? Bq : (z == 1) ? Bk : Bv;
    bf16* out         = (z == 0) ? Oq : (z == 1) ? Ok : Ov;
    const bf16* BT = WT + (size_t)z * 262144;
    const float scale = (z == 0) ? 0.125f : 1.0f;

    const int tid  = threadIdx.x;
    const int lane = tid & 63;
    const int wave = tid >> 6;
    const int quad = lane >> 4;
    const int l16  = lane & 15;
    const int mblk = blockIdx.x * 128;
    const int nblk = blockIdx.y * 128;

    const int srow = wave * 16 + (lane >> 2);
    const int scol = (lane & 3) * 8;
    const float* Ag = A + (size_t)(mblk + srow) * 512 + scol;
    const bf16* Bg  = BT + (size_t)(nblk + srow) * 512 + scol;
    bf16* Alp = Asm + srow * 32 + scol;      // per-lane A write addr
    bf16* Bl  = Bsm + wave * 16 * 32;        // wave-uniform lds-DMA base

    const int wr = (wave >> 1) * 32;
    const int wc = (wave & 1) * 64;

    floatx4 acc[2][4] = {};
    for (int k0 = 0; k0 < 512; k0 += 32) {
        gload_lds16(Bg + k0, Bl);
        float4 x0 = *(const float4*)(Ag + k0);
        float4 x1 = *(const float4*)(Ag + k0 + 4);
        Pack8 pa;
        pa.h[0] = (bf16)x0.x; pa.h[1] = (bf16)x0.y;
        pa.h[2] = (bf16)x0.z; pa.h[3] = (bf16)x0.w;
        pa.h[4] = (bf16)x1.x; pa.h[5] = (bf16)x1.y;
        pa.h[6] = (bf16)x1.z; pa.h[7] = (bf16)x1.w;
        *(uint4*)Alp = pa.u;
        __syncthreads();
        bf16x8 a[2], b[4];
        #pragma unroll
        for (int mt = 0; mt < 2; mt++)
            a[mt] = *(const bf16x8*)(Asm + (wr + mt * 16 + l16) * 32 + quad * 8);
        #pragma unroll
        for (int nt = 0; nt < 4; nt++)
            b[nt] = *(const bf16x8*)(Bsm + (wc + nt * 16 + l16) * 32 + quad * 8);
        #pragma unroll
        for (int mt = 0; mt < 2; mt++)
            #pragma unroll
            for (int nt = 0; nt < 4; nt++)
                acc[mt][nt] = __builtin_amdgcn_mfma_f32_16x16x32_bf16(
                    a[mt], b[nt], acc[mt][nt], 0, 0, 0);
        __syncthreads();
    }

    if (z != 2) {
        #pragma unroll
        for (int mt = 0; mt < 2; mt++) {
            #pragma unroll
            for (int nt = 0; nt < 4; nt++) {
                const int colg = nblk + wc + nt * 16 + l16;
                const float bb = bias[colg];
                #pragma unroll
                for (int r = 0; r < 4; r++) {
                    const int rowg = mblk + wr + mt * 16 + quad * 4 + r;
                    const float v = (acc[mt][nt][r] + bb) * scale;
                    const int b_ = rowg >> 12;
                    const int t_ = (rowg >> 3) & 511;
                    const int c  = rowg & 7;
                    const int h  = colg >> 6;
                    const int d  = colg & 63;
                    const int hd = b_ * 64 + h * 8 + c;
                    out[((size_t)hd * 512 + t_) * 64 + d] = (bf16)v;
                }
            }
        }
    } else {
        #pragma unroll
        for (int mt = 0; mt < 2; mt++) {
            #pragma unroll
            for (int nt = 0; nt < 4; nt++) {
                const int cl = wc + nt * 16 + l16;
                const float bb = bias[nblk + cl];
                #pragma unroll
                for (int r = 0; r < 4; r++)
                    Tsm[wr + mt * 16 + quad * 4 + r][cl] =
                        (bf16)(acc[mt][nt][r] + bb);
            }
        }
        __syncthreads();
        const int b_ = mblk >> 12;
        const int t0 = (mblk >> 3) & 511;
        #pragma unroll
        for (int ch = tid; ch < 1024; ch += 512) {
            const int col = ch >> 3, c = ch & 7;
            const int h = (nblk + col) >> 6, d = (nblk + col) & 63;
            const int hd = b_ * 64 + h * 8 + c;
            Pack8 lo, hi;
            #pragma unroll
            for (int j = 0; j < 8; j++) lo.h[j] = Tsm[j * 8 + c][col];
            #pragma unroll
            for (int j = 0; j < 8; j++) hi.h[j] = Tsm[(j + 8) * 8 + c][col];
            bf16* dst = out + ((size_t)hd * 64 + d) * 512 + t0;
            *(uint4*)dst = lo.u;
            *(uint4*)(dst + 8) = hi.u;
        }
    }
}

// ---------------- output projection GEMM: 8 waves, 128x128, BK=32 ------------
__global__ __launch_bounds__(512, 4) void gemm_o(
    const bf16* __restrict__ A, const bf16* __restrict__ BT,
    const float* __restrict__ bias, float* __restrict__ out)
{
    __shared__ bf16 Asm[128 * 32];
    __shared__ bf16 Bsm[128 * 32];
    const int tid  = threadIdx.x;
    const int lane = tid & 63;
    const int wave = tid >> 6;
    const int quad = lane >> 4;
    const int l16  = lane & 15;
    const int mblk = blockIdx.x * 128;
    const int nblk = blockIdx.y * 128;

    const int srow = wave * 16 + (lane >> 2);
    const int scol = (lane & 3) * 8;
    const bf16* Ag = A + (size_t)(mblk + srow) * 512 + scol;
    const bf16* Bg = BT + (size_t)(nblk + srow) * 512 + scol;
    bf16* Al = Asm + wave * 16 * 32;
    bf16* Bl = Bsm + wave * 16 * 32;

    const int wr = (wave >> 1) * 32;
    const int wc = (wave & 1) * 64;

    floatx4 acc[2][4] = {};
    for (int k0 = 0; k0 < 512; k0 += 32) {
        gload_lds16(Ag + k0, Al);
        gload_lds16(Bg + k0, Bl);
        __syncthreads();
        bf16x8 a[2], b[4];
        #pragma unroll
        for (int mt = 0; mt < 2; mt++)
            a[mt] = *(const bf16x8*)(Asm + (wr + mt * 16 + l16) * 32 + quad * 8);
        #pragma unroll
        for (int nt = 0; nt < 4; nt++)
            b[nt] = *(const bf16x8*)(Bsm + (wc + nt * 16 + l16) * 32 + quad * 8);
        #pragma unroll
        for (int mt = 0; mt < 2; mt++)
            #pragma unroll
            for (int nt = 0; nt < 4; nt++)
                acc[mt][nt] = __builtin_amdgcn_mfma_f32_16x16x32_bf16(
                    a[mt], b[nt], acc[mt][nt], 0, 0, 0);
        __syncthreads();
    }

    #pragma unroll
    for (int mt = 0; mt < 2; mt++) {
        #pragma unroll
        for (int nt = 0; nt < 4; nt++) {
            const int colg = nblk + wc + nt * 16 + l16;
            const float bb = bias[colg];
            #pragma unroll
            for (int r = 0; r < 4; r++) {
                const int rowg = mblk + wr + mt * 16 + quad * 4 + r;
                out[(size_t)rowg * 512 + colg] = acc[mt][nt][r] + bb;
            }
        }
    }
}

// ---------------- attention: QBLK=64, swapped QK^T ---------------------------
// mfma(K,Q) puts keys in (quad,r) and queries in l16: per lane, 4 consecutive
// keys per (s,nt) -> int4 mask loads (32 vs 128), ds_write_b64 P-writes
// (32 vs 128), and 2-step shuffle reduces (xor 16,32 across quads only).
// PV and output unchanged from the proven round-3 kernel.
#define PST 520

__global__ __launch_bounds__(256, 2) void attn_kernel(
    const bf16* __restrict__ Qws, const bf16* __restrict__ Kws,
    const bf16* __restrict__ Vtws, const int* __restrict__ mask,
    bf16* __restrict__ Xws)
{
    __shared__ bf16 Psm[64][PST];
    __shared__ float redM[4][64];
    __shared__ float redS[4][64];
    const int tid  = threadIdx.x;
    const int wave = tid >> 6;
    const int lane = tid & 63;
    const int quad = lane >> 4;
    const int l16  = lane & 15;
    // XCD swizzle: 1024 blocks, XCD x owns heads [x*16, x*16+16).
    const int s_ = blockIdx.x;
    const int o_ = ((s_ & 7) << 7) | (s_ >> 3);
    const int hd = o_ >> 3;
    const int qt = o_ & 7;
    const int q0 = qt * 64;
    const int b = hd >> 6;
    const int h = (hd >> 3) & 7;
    const int c = hd & 7;

    const bf16* Qh = Qws + (size_t)hd * 512 * 64;
    const bf16* Kh = Kws + (size_t)hd * 512 * 64;
    const int* mp = mask + ((size_t)b * 512 + q0) * 512;

    bf16x8 aq[4][2];
    #pragma unroll
    for (int s = 0; s < 4; s++) {
        aq[s][0] = *(const bf16x8*)(Qh + (size_t)(q0 + s * 16 + l16) * 64 + quad * 8);
        aq[s][1] = *(const bf16x8*)(Qh + (size_t)(q0 + s * 16 + l16) * 64 + 32 + quad * 8);
    }

    floatx4 sv[4][8];
    #pragma unroll
    for (int s = 0; s < 4; s++)
        #pragma unroll
        for (int nt = 0; nt < 8; nt++)
            sv[s][nt] = (floatx4){0.f, 0.f, 0.f, 0.f};

    // S^T = K x Q: D row (quad*4+r) = key within chunk, D col (l16) = query.
    #pragma unroll
    for (int nt = 0; nt < 8; nt++) {
        const int s0 = wave * 128 + nt * 16;
        bf16x8 bk0 = *(const bf16x8*)(Kh + (size_t)(s0 + l16) * 64 + quad * 8);
        bf16x8 bk1 = *(const bf16x8*)(Kh + (size_t)(s0 + l16) * 64 + 32 + quad * 8);
        #pragma unroll
        for (int s = 0; s < 4; s++) {
            sv[s][nt] = __builtin_amdgcn_mfma_f32_16x16x32_bf16(
                bk0, aq[s][0], sv[s][nt], 0, 0, 0);
            sv[s][nt] = __builtin_amdgcn_mfma_f32_16x16x32_bf16(
                bk1, aq[s][1], sv[s][nt], 0, 0, 0);
        }
    }

    // mask add (int4: 4 consecutive keys) + per-query running max
    float mx[4] = {-3.0e38f, -3.0e38f, -3.0e38f, -3.0e38f};
    #pragma unroll
    for (int s = 0; s < 4; s++)
        #pragma unroll
        for (int nt = 0; nt < 8; nt++) {
            const int4 mv = *(const int4*)(
                mp + (size_t)(s * 16 + l16) * 512 + wave * 128 + nt * 16 + quad * 4);
            float v0 = sv[s][nt][0] + ((mv.x == 0) ? -1.0e9f : 0.0f);
            float v1 = sv[s][nt][1] + ((mv.y == 0) ? -1.0e9f : 0.0f);
            float v2 = sv[s][nt][2] + ((mv.z == 0) ? -1.0e9f : 0.0f);
            float v3 = sv[s][nt][3] + ((mv.w == 0) ? -1.0e9f : 0.0f);
            sv[s][nt][0] = v0; sv[s][nt][1] = v1;
            sv[s][nt][2] = v2; sv[s][nt][3] = v3;
            mx[s] = fmaxf(mx[s], fmaxf(fmaxf(v0, v1), fmaxf(v2, v3)));
        }
    #pragma unroll
    for (int s = 0; s < 4; s++) {
        mx[s] = fmaxf(mx[s], __shfl_xor(mx[s], 16, 64));
        mx[s] = fmaxf(mx[s], __shfl_xor(mx[s], 32, 64));
    }
    if (quad == 0)
        #pragma unroll
        for (int s = 0; s < 4; s++) redM[wave][s * 16 + l16] = mx[s];
    __syncthreads();

    float mf[4], sum[4] = {0.f, 0.f, 0.f, 0.f};
    #pragma unroll
    for (int s = 0; s < 4; s++) {
        const int qr = s * 16 + l16;
        mf[s] = fmaxf(fmaxf(redM[0][qr], redM[1][qr]),
                      fmaxf(redM[2][qr], redM[3][qr]));
    }
    #pragma unroll
    for (int s = 0; s < 4; s++)
        #pragma unroll
        for (int nt = 0; nt < 8; nt++)
            #pragma unroll
            for (int r = 0; r < 4; r++) {
                const float e = __expf(sv[s][nt][r] - mf[s]);
                sv[s][nt][r] = e;
                sum[s] += e;
            }
    #pragma unroll
    for (int s = 0; s < 4; s++) {
        sum[s] += __shfl_xor(sum[s], 16, 64);
        sum[s] += __shfl_xor(sum[s], 32, 64);
    }
    if (quad == 0)
        #pragma unroll
        for (int s = 0; s < 4; s++) redS[wave][s * 16 + l16] = sum[s];
    __syncthreads();

    float inv[4];
    #pragma unroll
    for (int s = 0; s < 4; s++) {
        const int qr = s * 16 + l16;
        inv[s] = 1.f / (redS[0][qr] + redS[1][qr] + redS[2][qr] + redS[3][qr]);
    }
    #pragma unroll
    for (int s = 0; s < 4; s++)
        #pragma unroll
        for (int nt = 0; nt < 8; nt++) {
            Pack4 pk;
            #pragma unroll
            for (int r = 0; r < 4; r++)
                pk.h[r] = (bf16)(sv[s][nt][r] * inv[s]);
            *(unsigned long long*)&Psm[s * 16 + l16][wave * 128 + nt * 16 + quad * 4]
                = pk.u;
        }
    __syncthreads();

    const bf16* Vh = Vtws + (size_t)hd * 64 * 512;
    const int d0 = wave * 16;
    floatx4 o[4] = {};
    #pragma unroll
    for (int ks = 0; ks < 16; ks++) {
        bf16x8 bv = *(const bf16x8*)(Vh + (size_t)(d0 + l16) * 512 + ks * 32 + quad * 8);
        #pragma unroll
        for (int rt = 0; rt < 4; rt++) {
            bf16x8 ap = *(const bf16x8*)(&Psm[rt * 16 + l16][ks * 32 + quad * 8]);
            o[rt] = __builtin_amdgcn_mfma_f32_16x16x32_bf16(ap, bv, o[rt], 0, 0, 0);
        }
    }
    #pragma unroll
    for (int rt = 0; rt < 4; rt++)
        #pragma unroll
        for (int r = 0; r < 4; r++) {
            const int q = q0 + rt * 16 + quad * 4 + r;
            const size_t row = ((size_t)b * 512 + q) * 8 + c;
            Xws[row * 512 + h * 64 + d0 + l16] = (bf16)o[rt][r];
        }
}

extern "C" void kernel_launch(void* const* d_in, const int* in_sizes, int n_in,
                              void* d_out, int out_size, void* d_ws, size_t ws_size,
                              hipStream_t stream)
{
    const float* qin  = (const float*)d_in[0];
    const float* kin  = (const float*)d_in[1];
    const float* vin  = (const float*)d_in[2];
    const int*   mask = (const int*)d_in[3];
    const float* Bq = (const float*)d_in[5];
    const float* Bk = (const float*)d_in[7];
    const float* Bv = (const float*)d_in[9];
    const float* Bo = (const float*)d_in[11];
    float* out = (float*)d_out;

    const size_t R = (size_t)8192 * 512;
    bf16* r0 = (bf16*)d_ws;
    bf16* r1 = r0 + R;
    bf16* r2 = r1 + R;
    bf16* r3 = r2 + R;
    bf16* WT = r3 + R;

    wtr_kernel<<<dim3(8, 8, 4), dim3(256), 0, stream>>>(
        (const float*)d_in[4], (const float*)d_in[6],
        (const float*)d_in[8], (const float*)d_in[10], WT);
    gemm_qkv<<<dim3(64, 4, 3), dim3(512), 0, stream>>>(
        qin, kin, vin, WT, Bq, Bk, Bv, r0, r1, r2);
    attn_kernel<<<dim3(1024), dim3(256), 0, stream>>>(
        r0, r1, r2, mask, r3);
    gemm_o<<<dim3(64, 4), dim3(512), 0, stream>>>(
        r3, WT + (size_t)3 * 262144, Bo, out);
}